// Round 3
// baseline (112.760 us; speedup 1.0000x reference)
//
#include <hip/hip_runtime.h>
#include <stdint.h>

// Problem constants (fixed by setup_inputs: B=4, N_obj=8, N_v=2048)
#define NPTS 2048
#define KNN  16
#define AK   64
#define TPB  256
#define FPT  (NPTS / TPB)   // 8 points per thread (4-wave kernels)
#define KPL  (NPTS / 64)    // 32 points per lane (one wave per anchor)

typedef unsigned long long u64;
typedef unsigned int u32;
#define UMAX 0xFFFFFFFFFFFFFFFFull

// Exact float32 helpers (no FMA contraction -> match reference bitwise)
__device__ __forceinline__ float sq3(float x, float y, float z) {
    return __fadd_rn(__fadd_rn(__fmul_rn(x, x), __fmul_rn(y, y)), __fmul_rn(z, z));
}

// ---------------------------------------------------------------------------
// 64-lane butterfly reductions on u64 keys, ALL-VALU (no LDS/ds_bpermute).
// Stages 1,2,4,8: DPP permutations. quad_perm(1,0,3,2)=0xB1 is xor1;
// quad_perm(2,3,0,1)=0x4E is xor2; row_half_mirror(0x141)=xor4 once quads
// uniform; row_mirror(0x140)=xor8 once 8-groups uniform.
// Stages 16,32: gfx950 v_permlane16_swap / v_permlane32_swap with self;
// reducing with BOTH results realizes the xor exchange (self-compares are
// no-ops). Guarded by __has_builtin with shfl fallback. This exact butterfly
// is harness-verified (absmax 0.0) in the two previous rounds.
// ---------------------------------------------------------------------------
template <int CTRL>
__device__ __forceinline__ u64 dpp64(u64 k) {
    const int lo = __builtin_amdgcn_update_dpp((int)(u32)k, (int)(u32)k,
                                               CTRL, 0xF, 0xF, false);
    const int hi = __builtin_amdgcn_update_dpp((int)(u32)(k >> 32),
                                               (int)(u32)(k >> 32),
                                               CTRL, 0xF, 0xF, false);
    return ((u64)(u32)hi << 32) | (u32)lo;
}

__device__ __forceinline__ void swap16_pair(u64 k, u64& a, u64& b) {
#if __has_builtin(__builtin_amdgcn_permlane16_swap)
    const u32 lo = (u32)k, hi = (u32)(k >> 32);
    const auto rl = __builtin_amdgcn_permlane16_swap(lo, lo, false, false);
    const auto rh = __builtin_amdgcn_permlane16_swap(hi, hi, false, false);
    a = ((u64)(u32)rh[0] << 32) | (u32)rl[0];
    b = ((u64)(u32)rh[1] << 32) | (u32)rl[1];
#else
    a = (u64)__shfl_xor((long long)k, 16, 64);
    b = a;
#endif
}

__device__ __forceinline__ void swap32_pair(u64 k, u64& a, u64& b) {
#if __has_builtin(__builtin_amdgcn_permlane32_swap)
    const u32 lo = (u32)k, hi = (u32)(k >> 32);
    const auto rl = __builtin_amdgcn_permlane32_swap(lo, lo, false, false);
    const auto rh = __builtin_amdgcn_permlane32_swap(hi, hi, false, false);
    a = ((u64)(u32)rh[0] << 32) | (u32)rl[0];
    b = ((u64)(u32)rh[1] << 32) | (u32)rl[1];
#else
    a = (u64)__shfl_xor((long long)k, 32, 64);
    b = a;
#endif
}

__device__ __forceinline__ u64 wave_max64(u64 k) {
    u64 o, a, b;
    o = dpp64<0xB1>(k);  if (o > k) k = o;
    o = dpp64<0x4E>(k);  if (o > k) k = o;
    o = dpp64<0x141>(k); if (o > k) k = o;
    o = dpp64<0x140>(k); if (o > k) k = o;
    swap16_pair(k, a, b); if (a > k) k = a; if (b > k) k = b;
    swap32_pair(k, a, b); if (a > k) k = a; if (b > k) k = b;
    return k;
}

__device__ __forceinline__ u64 wave_min64(u64 k) {
    u64 o, a, b;
    o = dpp64<0xB1>(k);  if (o < k) k = o;
    o = dpp64<0x4E>(k);  if (o < k) k = o;
    o = dpp64<0x141>(k); if (o < k) k = o;
    o = dpp64<0x140>(k); if (o < k) k = o;
    swap16_pair(k, a, b); if (a < k) k = a; if (b < k) k = b;
    swap32_pair(k, a, b); if (a < k) k = a; if (b < k) k = b;
    return k;
}

// ---------------------------------------------------------------------------
// Kernel 1: farthest-point sampling, one block (4 waves) per object.
// Calibrated from rounds 0-2: each LDS round trip at 1-wave/SIMD costs
// ~250 cyc and the old step had three of them. This version removes LDS
// round trips rather than instructions:
//  - scan tracks the best point's COORDS in registers (bx,by,bz; +3
//    cndmask/pt, all compile-time indexed). The winner lane (key==wk,
//    unique since keys embed j) writes key+coords directly -> the
//    pre-barrier sP[widx] fetch AND the whole 32KB sP tile disappear.
//  - transposed exchange block (skey[4]|sx[4]|sy[4]|sz[4] per side):
//    post-barrier read is 5 vector loads (2xb128 keys + 3xb128 coords)
//    instead of 8, merged by one 3-compare tree selecting key and coords.
//  - anchors buffered in LDS, one coalesced store at the end (loop stays
//    vmem-free so the barrier's vmcnt drain is trivial).
// One barrier per step; double-buffered sides -> slot reuse is two barriers
// away, race-free.
// ---------------------------------------------------------------------------
__global__ __launch_bounds__(TPB) void fps_kernel(const float* __restrict__ pos,
                                                  int* __restrict__ anchors) {
    const int obj = blockIdx.x;
    const int t = threadIdx.x;
    const int wid = t >> 6;

    __shared__ alignas(16) u64 skey[8];    // [side*4 + wid], double-buffered
    __shared__ alignas(16) float sx[8];
    __shared__ alignas(16) float sy[8];
    __shared__ alignas(16) float sz[8];
    __shared__ int sAnc[AK];               // flushed once at the end

    const float* pts = pos + (size_t)obj * NPTS * 3;
    float px[FPT], py[FPT], pz[FPT], mind[FPT];
    #pragma unroll
    for (int i = 0; i < FPT; i++) {
        const int j = t + i * TPB;
        px[i] = pts[j * 3 + 0];
        py[i] = pts[j * 3 + 1];
        pz[i] = pts[j * 3 + 2];
    }
    if (t == 0) sAnc[0] = 0;

    // seed coords of point 0: uniform address -> scalar loads, same bits as
    // the staged values previously read from LDS.
    const float ax0 = pts[0], ay0 = pts[1], az0 = pts[2];

    float bv = -1.0f, bx = 0.f, by = 0.f, bz = 0.f; u32 bj = 0;
    #pragma unroll
    for (int i = 0; i < FPT; i++) {
        const float d2 = sq3(__fsub_rn(px[i], ax0), __fsub_rn(py[i], ay0),
                             __fsub_rn(pz[i], az0));
        mind[i] = d2;
        if (d2 > bv) {   // strict: smallest j kept on ties
            bv = d2; bj = (u32)(t + i * TPB);
            bx = px[i]; by = py[i]; bz = pz[i];
        }
    }
    // mind >= 0 -> float bits order-monotonic; ~j -> smaller j wins ties
    u64 key = ((u64)__float_as_uint(bv) << 32) | (u32)(~bj);

    #pragma unroll 1
    for (int s = 1; s < AK; s++) {
        const u64 wk = wave_max64(key);     // all lanes hold wave-winner key
        const int side = (s & 1) * 4;
        if (key == wk) {                    // exactly one lane per wave
            skey[side + wid] = wk;
            sx[side + wid] = bx;
            sy[side + wid] = by;
            sz[side + wid] = bz;
        }
        __syncthreads();   // only barrier per step; no vmem outstanding

        // 5 vector loads + 3-compare tree (keys unique -> no tie handling)
        const ulonglong2 k01 = *(const ulonglong2*)&skey[side];
        const ulonglong2 k23 = *(const ulonglong2*)&skey[side + 2];
        const float4 vx = *(const float4*)&sx[side];
        const float4 vy = *(const float4*)&sy[side];
        const float4 vz = *(const float4*)&sz[side];
        u64 ka = k01.x; float cx = vx.x, cy = vy.x, cz = vz.x;
        if (k01.y > ka) { ka = k01.y; cx = vx.y; cy = vy.y; cz = vz.y; }
        if (k23.x > ka) { ka = k23.x; cx = vx.z; cy = vy.z; cz = vz.z; }
        if (k23.y > ka) { ka = k23.y; cx = vx.w; cy = vy.w; cz = vz.w; }

        if (t == 0) sAnc[s] = (int)(~(u32)ka);
        if (s == AK - 1) break;   // no update needed after last anchor

        // fused min-update + argmax scan (exact: direct (p-b)^2 like lax.scan)
        bv = -1.0f; bj = 0;
        #pragma unroll
        for (int i = 0; i < FPT; i++) {
            const float d2 = sq3(__fsub_rn(px[i], cx), __fsub_rn(py[i], cy),
                                 __fsub_rn(pz[i], cz));
            const float nm = fminf(mind[i], d2);
            mind[i] = nm;
            if (nm > bv) {
                bv = nm; bj = (u32)(t + i * TPB);
                bx = px[i]; by = py[i]; bz = pz[i];
            }
        }
        key = ((u64)__float_as_uint(bv) << 32) | (u32)(~bj);
    }

    __syncthreads();
    if (t < AK) anchors[obj * AK + t] = sAnc[t];   // one coalesced store
}

// ---------------------------------------------------------------------------
// Kernel 2: KNN dist-vec + gather + concat. ONE WAVE per anchor, 4 anchors
// per block. (Byte-identical to the harness-verified round-2 version;
// deliberately untouched to isolate the fps change.)
// ---------------------------------------------------------------------------
__global__ __launch_bounds__(TPB) void knn_gather_kernel(
    const float* __restrict__ pos, const float* __restrict__ vel,
    const float* __restrict__ phys, const float* __restrict__ refp,
    const int* __restrict__ anchors, float* __restrict__ out) {
    const int t = threadIdx.x;
    const int wid = t >> 6, lane = t & 63;
    const int g = blockIdx.x * 4 + wid;   // global anchor id (obj*64 + k)
    const int obj = g >> 6;

    __shared__ float4 sP[NPTS];           // (x,y,z,sq) per point, 32 KB
    const float* pts = pos + (size_t)obj * NPTS * 3;
    #pragma unroll
    for (int i = 0; i < FPT; i++) {
        const int j = t + i * TPB;
        const float x = pts[j * 3 + 0];
        const float y = pts[j * 3 + 1];
        const float z = pts[j * 3 + 2];
        sP[j] = make_float4(x, y, z, sq3(x, y, z));
    }
    const int a = anchors[g];   // global read, no LDS hazard
    __syncthreads();            // the only barrier

    const float4 ca = sP[a];
    const float ax = ca.x, ay = ca.y, az = ca.z;
    const float sqa = ca.w;     // identical bits to reference's sq[a]

    // d2 row exactly as reference: (sq_a + sq_j) - 2*dot, sign-flip sortable.
    u64 k[KPL];
    #pragma unroll
    for (int i = 0; i < KPL; i++) {
        const int j = lane + i * 64;
        const float4 p = sP[j];
        const float dot = __fadd_rn(
            __fadd_rn(__fmul_rn(ax, p.x), __fmul_rn(ay, p.y)), __fmul_rn(az, p.z));
        const float d2 = __fsub_rn(__fadd_rn(sqa, p.w), __fmul_rn(2.0f, dot));
        u32 bb = __float_as_uint(d2);
        bb ^= (bb & 0x80000000u) ? 0xFFFFFFFFu : 0x80000000u;
        k[i] = (j == a) ? UMAX : (((u64)bb << 32) | (u32)j);
    }

    // per-lane 4 smallest, ascending: c0 < c1 < c2 < c3 (keys unique)
    u64 c0 = UMAX, c1 = UMAX, c2 = UMAX, c3 = UMAX;
    #pragma unroll
    for (int i = 0; i < KPL; i++) c0 = (k[i] < c0) ? k[i] : c0;
    #pragma unroll
    for (int i = 0; i < KPL; i++) {
        const u64 v = (k[i] > c0) ? k[i] : UMAX; c1 = (v < c1) ? v : c1;
    }
    #pragma unroll
    for (int i = 0; i < KPL; i++) {
        const u64 v = (k[i] > c1) ? k[i] : UMAX; c2 = (v < c2) ? v : c2;
    }
    #pragma unroll
    for (int i = 0; i < KPL; i++) {
        const u64 v = (k[i] > c2) ? k[i] : UMAX; c3 = (v < c3) ? v : c3;
    }

    float accx = 0.f, accy = 0.f, accz = 0.f;
    u64 thr = 0;
    float4 cw;
    {
        // round 0: every lane has >=4 real candidates -> no refill possible
        const u64 w = wave_min64(c0);
        cw = sP[(int)(u32)w];              // issue read; consumed next round
        if (c0 == w) { thr = c0; c0 = c1; c1 = c2; c2 = c3; c3 = UMAX; }
    }
    #pragma unroll 1
    for (int r = 1; r < KNN; r++) {
        if (c0 == UMAX) {   // rare refill: 4 smallest keys > thr (c1..c3 UMAX here)
            #pragma unroll
            for (int i = 0; i < KPL; i++) {
                const u64 v = (k[i] > thr) ? k[i] : UMAX; c0 = (v < c0) ? v : c0;
            }
            #pragma unroll
            for (int i = 0; i < KPL; i++) {
                const u64 v = (k[i] > c0) ? k[i] : UMAX; c1 = (v < c1) ? v : c1;
            }
            #pragma unroll
            for (int i = 0; i < KPL; i++) {
                const u64 v = (k[i] > c1) ? k[i] : UMAX; c2 = (v < c2) ? v : c2;
            }
            #pragma unroll
            for (int i = 0; i < KPL; i++) {
                const u64 v = (k[i] > c2) ? k[i] : UMAX; c3 = (v < c3) ? v : c3;
            }
        }
        const u64 w = wave_min64(c0);       // global min; ties impossible
        const float4 cn = sP[(int)(u32)w];  // issue this round's read...
        // ...and accumulate LAST round's winner under its latency (exact order)
        accx = __fadd_rn(accx, __fsub_rn(cw.x, ax));
        accy = __fadd_rn(accy, __fsub_rn(cw.y, ay));
        accz = __fadd_rn(accz, __fsub_rn(cw.z, az));
        cw = cn;
        if (c0 == w) {                      // exactly one lane pops
            thr = c0; c0 = c1; c1 = c2; c2 = c3; c3 = UMAX;
        }
    }
    accx = __fadd_rn(accx, __fsub_rn(cw.x, ax));
    accy = __fadd_rn(accy, __fsub_rn(cw.y, ay));
    accz = __fadd_rn(accz, __fsub_rn(cw.z, az));

    if (lane == 0) {
        float* o = out + (size_t)g * 12;
        o[0] = __fmul_rn(accx, 0.0625f);   // /16 exact as *2^-4
        o[1] = __fmul_rn(accy, 0.0625f);
        o[2] = __fmul_rn(accz, 0.0625f);
        const size_t base = (size_t)obj * NPTS * 3 + (size_t)a * 3;
        o[3] = vel[base + 0];
        o[4] = vel[base + 1];
        o[5] = vel[base + 2];
        o[6] = __fsub_rn(pos[base + 0], refp[base + 0]);
        o[7] = __fsub_rn(pos[base + 1], refp[base + 1]);
        o[8] = __fsub_rn(pos[base + 2], refp[base + 2]);
        const float* ph = phys + (size_t)obj * 3;
        o[9]  = ph[0];
        o[10] = ph[1];
        o[11] = ph[2];
    }
}

extern "C" void kernel_launch(void* const* d_in, const int* in_sizes, int n_in,
                              void* d_out, int out_size, void* d_ws, size_t ws_size,
                              hipStream_t stream) {
    const float* pos  = (const float*)d_in[0];  // (4,8,2048,3)
    const float* vel  = (const float*)d_in[1];  // (4,8,2048,3)
    const float* phys = (const float*)d_in[2];  // (4,8,3)
    const float* refp = (const float*)d_in[3];  // (4,8,2048,3)
    float* out = (float*)d_out;                 // (4,8,64,12)

    const int n_obj = in_sizes[2] / 3;          // 32 objects
    int* anchors = (int*)d_ws;                  // n_obj * 64 ints

    fps_kernel<<<n_obj, TPB, 0, stream>>>(pos, anchors);
    knn_gather_kernel<<<n_obj * AK / 4, TPB, 0, stream>>>(pos, vel, phys, refp,
                                                          anchors, out);
}